// Round 4
// baseline (709.500 us; speedup 1.0000x reference)
//
#include <hip/hip_runtime.h>
#include <math.h>

// ---------------------------------------------------------------------------
// GraphSAGE 3-layer forward, transform-then-aggregate, bf16 gather payloads.
//   K1: y1l = bf16(x@W1l), y1r = x@W1r + b1 (fp32)
//   K2: h1 = relu(norm(mean_gather(y1l) + y1r)); y2l = bf16(h1@W2l), y2r fp32
//   K3: h2 = relu(norm(mean_gather(y2l) + y2r)); y3l = bf16(h2@W3l), y3r fp32
//   K4: o  = norm(mean_gather(y3l) + y3r); log_softmax -> out
// Gather rows: 128/64/32 B -> 8/16/32 neighbors in flight per wave (uint4
// loads of 8 bf16 per lane). fp32 accumulation throughout; bf16 only on the
// gathered operand (error ~2^-9 relative, well under 6.56e-2 threshold).
// ---------------------------------------------------------------------------

__device__ __forceinline__ unsigned short f2bf(float f) {   // RNE
    unsigned u = __float_as_uint(f);
    u += 0x7fffu + ((u >> 16) & 1u);
    return (unsigned short)(u >> 16);
}
__device__ __forceinline__ float blo(unsigned u) { return __uint_as_float(u << 16); }
__device__ __forceinline__ float bhi(unsigned u) { return __uint_as_float(u & 0xffff0000u); }

__global__ void degree_kernel(const int* __restrict__ ei, int* __restrict__ deg, int E) {
    int e = blockIdx.x * blockDim.x + threadIdx.x;
    if (e < E) atomicAdd(&deg[ei[E + e]], 1);
}

__global__ __launch_bounds__(1024) void scan_block_kernel(
        const int* __restrict__ deg, int* __restrict__ rowptr,
        int* __restrict__ cursor, int* __restrict__ counter, int n) {
    __shared__ int buf[1024];
    __shared__ int base_s;
    const int i = blockIdx.x * 1024 + threadIdx.x;
    const int v = (i < n) ? deg[i] : 0;
    buf[threadIdx.x] = v;
    __syncthreads();
    for (int off = 1; off < 1024; off <<= 1) {
        int t = (threadIdx.x >= (unsigned)off) ? buf[threadIdx.x - off] : 0;
        __syncthreads();
        buf[threadIdx.x] += t;
        __syncthreads();
    }
    if (threadIdx.x == 0) base_s = atomicAdd(counter, buf[1023]);
    __syncthreads();
    const int excl = buf[threadIdx.x] - v + base_s;
    if (i < n) { rowptr[i] = excl; cursor[i] = excl; }
}

__global__ void build_csr_kernel(const int* __restrict__ ei, int* __restrict__ cursor,
                                 int* __restrict__ col, int E) {
    int e = blockIdx.x * blockDim.x + threadIdx.x;
    if (e < E) {
        int pos = atomicAdd(&cursor[ei[E + e]], 1);
        col[pos] = ei[e];
    }
}

// K1: dense per-node transform of x (64 -> 64 both matrices), yl stored bf16.
__global__ __launch_bounds__(256) void transform1_kernel(
        const float* __restrict__ x, const float* __restrict__ Wl,
        const float* __restrict__ Wr, const float* __restrict__ b,
        unsigned short* __restrict__ yl, float* __restrict__ yr, int n) {
    __shared__ float sWl[64 * 64];
    __shared__ float sWr[64 * 64];
    __shared__ float sb[64];
    for (int i = threadIdx.x; i < 64 * 64; i += 256) { sWl[i] = Wl[i]; sWr[i] = Wr[i]; }
    if (threadIdx.x < 64) sb[threadIdx.x] = b[threadIdx.x];
    __syncthreads();
    const int lane = threadIdx.x & 63;
    const int node = blockIdx.x * 4 + (threadIdx.x >> 6);
    if (node >= n) return;
    const float xi = x[(size_t)node * 64 + lane];
    float accl = 0.f, accr = sb[lane];
#pragma unroll
    for (int k = 0; k < 64; ++k) {
        const float xk = __shfl(xi, k);
        accl += xk * sWl[k * 64 + lane];
        accr += xk * sWr[k * 64 + lane];
    }
    yl[(size_t)node * 64 + lane] = f2bf(accl);
    yr[(size_t)node * 64 + lane] = accr;
}

// Gather mean of bf16 rows (width F_IN) -> lane-per-feature fp32 value.
// Returns value for lane < F_IN (garbage above).
template <int F_IN>
__device__ __forceinline__ float gather_mean_bf16(
        const unsigned short* __restrict__ yl_in, const int* __restrict__ col,
        int beg, int end, float inv, int lane) {
    constexpr int NCH = F_IN / 8;        // 16B chunks per row
    constexpr int SUBS = 64 / NCH;       // neighbors in flight per wave
    const int ch  = lane % NCH;
    const int sub = lane / NCH;
    float a0 = 0.f, a1 = 0.f, a2 = 0.f, a3 = 0.f, a4 = 0.f, a5 = 0.f, a6 = 0.f, a7 = 0.f;
    for (int e = beg + sub; e < end; e += SUBS) {
        const int nbr = col[e];
        const uint4 t = *(const uint4*)(yl_in + (size_t)nbr * F_IN + ch * 8);
        a0 += blo(t.x); a1 += bhi(t.x);
        a2 += blo(t.y); a3 += bhi(t.y);
        a4 += blo(t.z); a5 += bhi(t.z);
        a6 += blo(t.w); a7 += bhi(t.w);
    }
#pragma unroll
    for (int off = NCH; off < 64; off <<= 1) {
        a0 += __shfl_xor(a0, off); a1 += __shfl_xor(a1, off);
        a2 += __shfl_xor(a2, off); a3 += __shfl_xor(a3, off);
        a4 += __shfl_xor(a4, off); a5 += __shfl_xor(a5, off);
        a6 += __shfl_xor(a6, off); a7 += __shfl_xor(a7, off);
    }
    // relayout: feature f = ch*8 + j ; lane f pulls a[j] from lane (f>>3)
    const int src = lane >> 3;
    const int j   = lane & 7;
    const float g0 = __shfl(a0, src), g1 = __shfl(a1, src), g2 = __shfl(a2, src),
                g3 = __shfl(a3, src), g4 = __shfl(a4, src), g5 = __shfl(a5, src),
                g6 = __shfl(a6, src), g7 = __shfl(a7, src);
    const float lo = (j & 2) ? ((j & 1) ? g3 : g2) : ((j & 1) ? g1 : g0);
    const float hi = (j & 2) ? ((j & 1) ? g7 : g6) : ((j & 1) ? g5 : g4);
    return ((j & 4) ? hi : lo) * inv;
}

// K2/K3: gather + norm + relu + next-layer transform (yl_out bf16).
template <int F_IN, int F_OUT, int F_PAD>
__global__ __launch_bounds__(256) void gt_kernel(
        const unsigned short* __restrict__ yl_in, const float* __restrict__ yr_in,
        const int* __restrict__ rowptr, const int* __restrict__ deg_arr,
        const int* __restrict__ col,
        const float* __restrict__ Wl, const float* __restrict__ Wr,
        const float* __restrict__ b,
        unsigned short* __restrict__ yl_out, float* __restrict__ yr_out, int n) {
    __shared__ float sWl[F_IN * F_OUT];
    __shared__ float sWr[F_IN * F_OUT];
    __shared__ float sb[F_OUT];
    for (int i = threadIdx.x; i < F_IN * F_OUT; i += 256) { sWl[i] = Wl[i]; sWr[i] = Wr[i]; }
    if (threadIdx.x < F_OUT) sb[threadIdx.x] = b[threadIdx.x];
    __syncthreads();

    const int lane = threadIdx.x & 63;
    const int node = blockIdx.x * 4 + (threadIdx.x >> 6);
    if (node >= n) return;

    const int dg  = deg_arr[node];
    const int beg = rowptr[node];
    const float inv = (dg > 0) ? 1.f / (float)dg : 0.f;
    const float hv = gather_mean_bf16<F_IN>(yl_in, col, beg, beg + dg, inv, lane);

    const float o = (lane < F_IN) ? hv + yr_in[(size_t)node * F_IN + lane] : 0.f;
    float s2 = o * o;
#pragma unroll
    for (int off = 1; off < 64; off <<= 1) s2 += __shfl_xor(s2, off);
    const float h = fmaxf(o * (1.f / fmaxf(sqrtf(s2), 1e-12f)), 0.f);  // norm + relu

    float accl = 0.f, accr = (lane < F_OUT) ? sb[lane] : 0.f;
#pragma unroll
    for (int k = 0; k < F_IN; ++k) {
        const float hk = __shfl(h, k);
        if (lane < F_OUT) {
            accl += hk * sWl[k * F_OUT + lane];
            accr += hk * sWr[k * F_OUT + lane];
        }
    }
    if (lane < F_PAD) {
        yl_out[(size_t)node * F_PAD + lane] = (lane < F_OUT) ? f2bf(accl) : (unsigned short)0;
        yr_out[(size_t)node * F_PAD + lane] = (lane < F_OUT) ? accr : 0.f;
    }
}

// K4: gather width 16 (10 real), norm, log_softmax.
__global__ __launch_bounds__(256) void final_kernel(
        const unsigned short* __restrict__ yl_in, const float* __restrict__ yr_in,
        const int* __restrict__ rowptr, const int* __restrict__ deg_arr,
        const int* __restrict__ col, float* __restrict__ out, int n) {
    const int lane = threadIdx.x & 63;
    const int node = blockIdx.x * 4 + (threadIdx.x >> 6);
    if (node >= n) return;
    const int dg  = deg_arr[node];
    const int beg = rowptr[node];
    const float inv = (dg > 0) ? 1.f / (float)dg : 0.f;
    const float hv = gather_mean_bf16<16>(yl_in, col, beg, beg + dg, inv, lane);

    float o = (lane < 16) ? hv + yr_in[(size_t)node * 16 + lane] : 0.f;
    float s2 = o * o;
#pragma unroll
    for (int off = 1; off < 64; off <<= 1) s2 += __shfl_xor(s2, off);
    o *= 1.f / fmaxf(sqrtf(s2), 1e-12f);
    float m = (lane < 10) ? o : -INFINITY;
#pragma unroll
    for (int off = 1; off < 64; off <<= 1) m = fmaxf(m, __shfl_xor(m, off));
    float ex = (lane < 10) ? __expf(o - m) : 0.f;
    float s = ex;
#pragma unroll
    for (int off = 1; off < 64; off <<= 1) s += __shfl_xor(s, off);
    if (lane < 10) out[(size_t)node * 10 + lane] = o - m - logf(s);
}

extern "C" void kernel_launch(void* const* d_in, const int* in_sizes, int n_in,
                              void* d_out, int out_size, void* d_ws, size_t ws_size,
                              hipStream_t stream) {
    const float* x   = (const float*)d_in[0];
    const int*   ei  = (const int*)d_in[1];     // int64 in ref -> int32 on device
    const float* W1l = (const float*)d_in[2];
    const float* W1r = (const float*)d_in[3];
    const float* b1  = (const float*)d_in[4];
    const float* W2l = (const float*)d_in[5];
    const float* W2r = (const float*)d_in[6];
    const float* b2  = (const float*)d_in[7];
    const float* W3l = (const float*)d_in[8];
    const float* W3r = (const float*)d_in[9];
    const float* b3  = (const float*)d_in[10];
    float*       out = (float*)d_out;

    const int N = in_sizes[0] / 64;
    const int E = in_sizes[1] / 2;

    auto align16 = [](size_t v) { return (v + 15) & ~(size_t)15; };
    char* ws = (char*)d_ws;
    size_t off = 0;
    int* deg     = (int*)(ws + off); off = align16(off + (size_t)(N + 1) * 4);
    int* counter = deg + N;          // zeroed together with deg
    int* rowptr  = (int*)(ws + off); off = align16(off + (size_t)N * 4);
    int* cursor  = (int*)(ws + off); off = align16(off + (size_t)N * 4);
    int* colidx  = (int*)(ws + off); off = align16(off + (size_t)E * 4);
    unsigned short* y1l = (unsigned short*)(ws + off); off = align16(off + (size_t)N * 64 * 2);
    float*          y1r = (float*)(ws + off);          off = align16(off + (size_t)N * 64 * 4);
    unsigned short* y2l = (unsigned short*)(ws + off); off = align16(off + (size_t)N * 32 * 2);
    float*          y2r = (float*)(ws + off);          off = align16(off + (size_t)N * 32 * 4);
    unsigned short* y3l = (unsigned short*)(ws + off); off = align16(off + (size_t)N * 16 * 2);
    float*          y3r = (float*)(ws + off);          off = align16(off + (size_t)N * 16 * 4);
    (void)ws_size; (void)n_in; (void)out_size;

    // ---- CSR build
    hipMemsetAsync(deg, 0, (size_t)(N + 1) * 4, stream);
    degree_kernel<<<(E + 255) / 256, 256, 0, stream>>>(ei, deg, E);
    scan_block_kernel<<<(N + 1023) / 1024, 1024, 0, stream>>>(deg, rowptr, cursor, counter, N);
    build_csr_kernel<<<(E + 255) / 256, 256, 0, stream>>>(ei, cursor, colidx, E);

    // ---- layers
    const int blocks4 = (N + 3) / 4;
    transform1_kernel<<<blocks4, 256, 0, stream>>>(x, W1l, W1r, b1, y1l, y1r, N);
    gt_kernel<64, 32, 32><<<blocks4, 256, 0, stream>>>(y1l, y1r, rowptr, deg, colidx,
                                                       W2l, W2r, b2, y2l, y2r, N);
    gt_kernel<32, 10, 16><<<blocks4, 256, 0, stream>>>(y2l, y2r, rowptr, deg, colidx,
                                                       W3l, W3r, b3, y3l, y3r, N);
    final_kernel<<<blocks4, 256, 0, stream>>>(y3l, y3r, rowptr, deg, colidx, out, N);
}

// Round 5
// 681.154 us; speedup vs baseline: 1.0416x; 1.0416x over previous
//
#include <hip/hip_runtime.h>
#include <math.h>

// ---------------------------------------------------------------------------
// GraphSAGE 3-layer forward, transform-then-aggregate, bf16 gather payloads,
// persistent blocks (grid-stride node loops; weights staged in LDS ONCE per
// block, not once per 4 nodes — round-4 profiling showed per-block weight
// staging amortized over 4 nodes dominated all gather passes).
// ---------------------------------------------------------------------------

__device__ __forceinline__ unsigned short f2bf(float f) {   // RNE
    unsigned u = __float_as_uint(f);
    u += 0x7fffu + ((u >> 16) & 1u);
    return (unsigned short)(u >> 16);
}
__device__ __forceinline__ float blo(unsigned u) { return __uint_as_float(u << 16); }
__device__ __forceinline__ float bhi(unsigned u) { return __uint_as_float(u & 0xffff0000u); }

__global__ void degree_kernel(const int* __restrict__ ei, int* __restrict__ deg, int E) {
    int e = blockIdx.x * blockDim.x + threadIdx.x;
    if (e < E) atomicAdd(&deg[ei[E + e]], 1);
}

__global__ __launch_bounds__(1024) void scan_block_kernel(
        const int* __restrict__ deg, int* __restrict__ rowptr,
        int* __restrict__ cursor, int* __restrict__ counter, int n) {
    __shared__ int buf[1024];
    __shared__ int base_s;
    const int i = blockIdx.x * 1024 + threadIdx.x;
    const int v = (i < n) ? deg[i] : 0;
    buf[threadIdx.x] = v;
    __syncthreads();
    for (int off = 1; off < 1024; off <<= 1) {
        int t = (threadIdx.x >= (unsigned)off) ? buf[threadIdx.x - off] : 0;
        __syncthreads();
        buf[threadIdx.x] += t;
        __syncthreads();
    }
    if (threadIdx.x == 0) base_s = atomicAdd(counter, buf[1023]);
    __syncthreads();
    const int excl = buf[threadIdx.x] - v + base_s;
    if (i < n) { rowptr[i] = excl; cursor[i] = excl; }
}

__global__ void build_csr_kernel(const int* __restrict__ ei, int* __restrict__ cursor,
                                 int* __restrict__ col, int E) {
    int e = blockIdx.x * blockDim.x + threadIdx.x;
    if (e < E) {
        int pos = atomicAdd(&cursor[ei[E + e]], 1);
        col[pos] = ei[e];
    }
}

// K1: dense per-node transform of x (64 -> 64 both matrices), yl stored bf16.
// Persistent: weights staged once, grid-stride over nodes.
__global__ __launch_bounds__(256) void transform1_kernel(
        const float* __restrict__ x, const float* __restrict__ Wl,
        const float* __restrict__ Wr, const float* __restrict__ b,
        unsigned short* __restrict__ yl, float* __restrict__ yr, int n) {
    __shared__ float sWl[64 * 64];
    __shared__ float sWr[64 * 64];
    __shared__ float sb[64];
    for (int i = threadIdx.x; i < 64 * 64; i += 256) { sWl[i] = Wl[i]; sWr[i] = Wr[i]; }
    if (threadIdx.x < 64) sb[threadIdx.x] = b[threadIdx.x];
    __syncthreads();
    const int lane = threadIdx.x & 63;
    const int wave = threadIdx.x >> 6;
    const int stride = gridDim.x * 4;
    for (int node = blockIdx.x * 4 + wave; node < n; node += stride) {
        const float xi = x[(size_t)node * 64 + lane];
        float accl = 0.f, accr = sb[lane];
#pragma unroll
        for (int k = 0; k < 64; ++k) {
            const float xk = __shfl(xi, k);
            accl += xk * sWl[k * 64 + lane];
            accr += xk * sWr[k * 64 + lane];
        }
        yl[(size_t)node * 64 + lane] = f2bf(accl);
        yr[(size_t)node * 64 + lane] = accr;
    }
}

// Gather mean of bf16 rows (width F_IN) -> lane-per-feature fp32 value.
template <int F_IN>
__device__ __forceinline__ float gather_mean_bf16(
        const unsigned short* __restrict__ yl_in, const int* __restrict__ col,
        int beg, int end, float inv, int lane) {
    constexpr int NCH = F_IN / 8;        // 16B chunks per row
    constexpr int SUBS = 64 / NCH;       // neighbors in flight per wave
    const int ch  = lane % NCH;
    const int sub = lane / NCH;
    float a0 = 0.f, a1 = 0.f, a2 = 0.f, a3 = 0.f, a4 = 0.f, a5 = 0.f, a6 = 0.f, a7 = 0.f;
    for (int e = beg + sub; e < end; e += SUBS) {
        const int nbr = col[e];
        const uint4 t = *(const uint4*)(yl_in + (size_t)nbr * F_IN + ch * 8);
        a0 += blo(t.x); a1 += bhi(t.x);
        a2 += blo(t.y); a3 += bhi(t.y);
        a4 += blo(t.z); a5 += bhi(t.z);
        a6 += blo(t.w); a7 += bhi(t.w);
    }
#pragma unroll
    for (int off = NCH; off < 64; off <<= 1) {
        a0 += __shfl_xor(a0, off); a1 += __shfl_xor(a1, off);
        a2 += __shfl_xor(a2, off); a3 += __shfl_xor(a3, off);
        a4 += __shfl_xor(a4, off); a5 += __shfl_xor(a5, off);
        a6 += __shfl_xor(a6, off); a7 += __shfl_xor(a7, off);
    }
    // relayout: feature f = ch*8 + j ; lane f pulls a[j] from lane (f>>3)
    const int src = lane >> 3;
    const int j   = lane & 7;
    const float g0 = __shfl(a0, src), g1 = __shfl(a1, src), g2 = __shfl(a2, src),
                g3 = __shfl(a3, src), g4 = __shfl(a4, src), g5 = __shfl(a5, src),
                g6 = __shfl(a6, src), g7 = __shfl(a7, src);
    const float lo = (j & 2) ? ((j & 1) ? g3 : g2) : ((j & 1) ? g1 : g0);
    const float hi = (j & 2) ? ((j & 1) ? g7 : g6) : ((j & 1) ? g5 : g4);
    return ((j & 4) ? hi : lo) * inv;
}

// K2/K3: gather + norm + relu + next-layer transform (yl_out bf16).
// Persistent: weights staged once, grid-stride over nodes, no inner barriers.
template <int F_IN, int F_OUT, int F_PAD>
__global__ __launch_bounds__(256) void gt_kernel(
        const unsigned short* __restrict__ yl_in, const float* __restrict__ yr_in,
        const int* __restrict__ rowptr, const int* __restrict__ deg_arr,
        const int* __restrict__ col,
        const float* __restrict__ Wl, const float* __restrict__ Wr,
        const float* __restrict__ b,
        unsigned short* __restrict__ yl_out, float* __restrict__ yr_out, int n) {
    __shared__ float sWl[F_IN * F_OUT];
    __shared__ float sWr[F_IN * F_OUT];
    __shared__ float sb[F_OUT];
    for (int i = threadIdx.x; i < F_IN * F_OUT; i += 256) { sWl[i] = Wl[i]; sWr[i] = Wr[i]; }
    if (threadIdx.x < F_OUT) sb[threadIdx.x] = b[threadIdx.x];
    __syncthreads();

    const int lane = threadIdx.x & 63;
    const int wave = threadIdx.x >> 6;
    const int stride = gridDim.x * 4;
    for (int node = blockIdx.x * 4 + wave; node < n; node += stride) {
        const int dg  = deg_arr[node];
        const int beg = rowptr[node];
        const float inv = (dg > 0) ? 1.f / (float)dg : 0.f;
        const float hv = gather_mean_bf16<F_IN>(yl_in, col, beg, beg + dg, inv, lane);

        const float o = (lane < F_IN) ? hv + yr_in[(size_t)node * F_IN + lane] : 0.f;
        float s2 = o * o;
#pragma unroll
        for (int off = 1; off < 64; off <<= 1) s2 += __shfl_xor(s2, off);
        const float h = fmaxf(o * (1.f / fmaxf(sqrtf(s2), 1e-12f)), 0.f);  // norm+relu

        float accl = 0.f, accr = (lane < F_OUT) ? sb[lane] : 0.f;
#pragma unroll
        for (int k = 0; k < F_IN; ++k) {
            const float hk = __shfl(h, k);
            if (lane < F_OUT) {
                accl += hk * sWl[k * F_OUT + lane];
                accr += hk * sWr[k * F_OUT + lane];
            }
        }
        if (lane < F_PAD) {
            yl_out[(size_t)node * F_PAD + lane] = (lane < F_OUT) ? f2bf(accl) : (unsigned short)0;
            yr_out[(size_t)node * F_PAD + lane] = (lane < F_OUT) ? accr : 0.f;
        }
    }
}

// K4: gather width 16 (10 real), norm, log_softmax. Grid-stride.
__global__ __launch_bounds__(256) void final_kernel(
        const unsigned short* __restrict__ yl_in, const float* __restrict__ yr_in,
        const int* __restrict__ rowptr, const int* __restrict__ deg_arr,
        const int* __restrict__ col, float* __restrict__ out, int n) {
    const int lane = threadIdx.x & 63;
    const int wave = threadIdx.x >> 6;
    const int stride = gridDim.x * 4;
    for (int node = blockIdx.x * 4 + wave; node < n; node += stride) {
        const int dg  = deg_arr[node];
        const int beg = rowptr[node];
        const float inv = (dg > 0) ? 1.f / (float)dg : 0.f;
        const float hv = gather_mean_bf16<16>(yl_in, col, beg, beg + dg, inv, lane);

        float o = (lane < 16) ? hv + yr_in[(size_t)node * 16 + lane] : 0.f;
        float s2 = o * o;
#pragma unroll
        for (int off = 1; off < 64; off <<= 1) s2 += __shfl_xor(s2, off);
        o *= 1.f / fmaxf(sqrtf(s2), 1e-12f);
        float m = (lane < 10) ? o : -INFINITY;
#pragma unroll
        for (int off = 1; off < 64; off <<= 1) m = fmaxf(m, __shfl_xor(m, off));
        float ex = (lane < 10) ? __expf(o - m) : 0.f;
        float s = ex;
#pragma unroll
        for (int off = 1; off < 64; off <<= 1) s += __shfl_xor(s, off);
        if (lane < 10) out[(size_t)node * 10 + lane] = o - m - logf(s);
    }
}

extern "C" void kernel_launch(void* const* d_in, const int* in_sizes, int n_in,
                              void* d_out, int out_size, void* d_ws, size_t ws_size,
                              hipStream_t stream) {
    const float* x   = (const float*)d_in[0];
    const int*   ei  = (const int*)d_in[1];     // int64 in ref -> int32 on device
    const float* W1l = (const float*)d_in[2];
    const float* W1r = (const float*)d_in[3];
    const float* b1  = (const float*)d_in[4];
    const float* W2l = (const float*)d_in[5];
    const float* W2r = (const float*)d_in[6];
    const float* b2  = (const float*)d_in[7];
    const float* W3l = (const float*)d_in[8];
    const float* W3r = (const float*)d_in[9];
    const float* b3  = (const float*)d_in[10];
    float*       out = (float*)d_out;

    const int N = in_sizes[0] / 64;
    const int E = in_sizes[1] / 2;

    auto align16 = [](size_t v) { return (v + 15) & ~(size_t)15; };
    char* ws = (char*)d_ws;
    size_t off = 0;
    int* deg     = (int*)(ws + off); off = align16(off + (size_t)(N + 1) * 4);
    int* counter = deg + N;          // zeroed together with deg
    int* rowptr  = (int*)(ws + off); off = align16(off + (size_t)N * 4);
    int* cursor  = (int*)(ws + off); off = align16(off + (size_t)N * 4);
    int* colidx  = (int*)(ws + off); off = align16(off + (size_t)E * 4);
    unsigned short* y1l = (unsigned short*)(ws + off); off = align16(off + (size_t)N * 64 * 2);
    float*          y1r = (float*)(ws + off);          off = align16(off + (size_t)N * 64 * 4);
    unsigned short* y2l = (unsigned short*)(ws + off); off = align16(off + (size_t)N * 32 * 2);
    float*          y2r = (float*)(ws + off);          off = align16(off + (size_t)N * 32 * 4);
    unsigned short* y3l = (unsigned short*)(ws + off); off = align16(off + (size_t)N * 16 * 2);
    float*          y3r = (float*)(ws + off);          off = align16(off + (size_t)N * 16 * 4);
    (void)ws_size; (void)n_in; (void)out_size;

    // ---- CSR build
    hipMemsetAsync(deg, 0, (size_t)(N + 1) * 4, stream);
    degree_kernel<<<(E + 255) / 256, 256, 0, stream>>>(ei, deg, E);
    scan_block_kernel<<<(N + 1023) / 1024, 1024, 0, stream>>>(deg, rowptr, cursor, counter, N);
    build_csr_kernel<<<(E + 255) / 256, 256, 0, stream>>>(ei, cursor, colidx, E);

    // ---- layers (persistent blocks, grid-stride node loops)
    // transform1: 33KB LDS -> ~4 blocks/CU; 1024 blocks covers 256 CUs x4.
    transform1_kernel<<<1024, 256, 0, stream>>>(x, W1l, W1r, b1, y1l, y1r, N);
    // gt kernels: ~16.5KB LDS -> ~8-9 blocks/CU; 2048 blocks = 8/CU.
    gt_kernel<64, 32, 32><<<2048, 256, 0, stream>>>(y1l, y1r, rowptr, deg, colidx,
                                                    W2l, W2r, b2, y2l, y2r, N);
    gt_kernel<32, 10, 16><<<2048, 256, 0, stream>>>(y2l, y2r, rowptr, deg, colidx,
                                                    W3l, W3r, b3, y3l, y3r, N);
    final_kernel<<<2048, 256, 0, stream>>>(y3l, y3r, rowptr, deg, colidx, out, N);
}

// Round 6
// 356.371 us; speedup vs baseline: 1.9909x; 1.9114x over previous
//
#include <hip/hip_runtime.h>
#include <math.h>

// ---------------------------------------------------------------------------
// GraphSAGE 3-layer forward. Round-6 restructure:
//  - transform kernels: MFMA bf16 GEMM (16 nodes/wave), yl bf16 + yr fp32+bias
//  - aggregate kernels: sub-wave-per-node (8 lanes/node @F=64) register
//    accumulation — no reduce tree, no relayout, tiny epilogue (norm/relu or
//    log_softmax). R5 post-mortem: per-node shuffle-chain epilogue was the
//    bottleneck, not bytes, not LDS staging.
// Pipeline: CSR build; t1(x->y1) agg1(y1->h1) t2(h1->y2) agg2(y2->h2)
//           t3(h2->y3, pad 16) agg3(y3->out, log_softmax)
// ---------------------------------------------------------------------------

typedef __attribute__((ext_vector_type(8))) short short8;
typedef __attribute__((ext_vector_type(4))) float floatx4;

__device__ __forceinline__ unsigned short f2bf(float f) {   // RNE
    unsigned u = __float_as_uint(f);
    u += 0x7fffu + ((u >> 16) & 1u);
    return (unsigned short)(u >> 16);
}
__device__ __forceinline__ float blo(unsigned u) { return __uint_as_float(u << 16); }
__device__ __forceinline__ float bhi(unsigned u) { return __uint_as_float(u & 0xffff0000u); }

// ---------------- CSR build ----------------
__global__ void degree_kernel(const int* __restrict__ ei, int* __restrict__ deg, int E) {
    int e = blockIdx.x * blockDim.x + threadIdx.x;
    if (e < E) atomicAdd(&deg[ei[E + e]], 1);
}

__global__ __launch_bounds__(1024) void scan_block_kernel(
        const int* __restrict__ deg, int* __restrict__ rowptr,
        int* __restrict__ cursor, int* __restrict__ counter, int n) {
    __shared__ int buf[1024];
    __shared__ int base_s;
    const int i = blockIdx.x * 1024 + threadIdx.x;
    const int v = (i < n) ? deg[i] : 0;
    buf[threadIdx.x] = v;
    __syncthreads();
    for (int off = 1; off < 1024; off <<= 1) {
        int t = (threadIdx.x >= (unsigned)off) ? buf[threadIdx.x - off] : 0;
        __syncthreads();
        buf[threadIdx.x] += t;
        __syncthreads();
    }
    if (threadIdx.x == 0) base_s = atomicAdd(counter, buf[1023]);
    __syncthreads();
    const int excl = buf[threadIdx.x] - v + base_s;
    if (i < n) { rowptr[i] = excl; cursor[i] = excl; }
}

__global__ void build_csr_kernel(const int* __restrict__ ei, int* __restrict__ cursor,
                                 int* __restrict__ col, int E) {
    int e = blockIdx.x * blockDim.x + threadIdx.x;
    if (e < E) {
        int pos = atomicAdd(&cursor[ei[E + e]], 1);
        col[pos] = ei[e];
    }
}

// ---------------- MFMA transform: y_l = A@Wl (bf16), y_r = A@Wr + b (fp32) ---
// A: [n x K] (fp32 if AFP32 else bf16 row-major). Wl/Wr: [K x F_OUT] fp32.
// Outputs width PAD (>= F_OUT), pad cols written as exact zeros.
// Fragment layouts (gfx950 16x16x32 bf16, HW-verified per guide):
//   A: lane holds A[m=lane&15][k=q*8+j], q=lane>>4, j=0..7
//   B: lane holds B[k=q*8+j][n=lane&15]
//   D: lane reg r holds D[row=q*4+r][col=lane&15]
template <int K, int F_OUT, int PAD, bool AFP32>
__global__ __launch_bounds__(256) void transform_kernel(
        const void* __restrict__ Ain, const float* __restrict__ Wl,
        const float* __restrict__ Wr, const float* __restrict__ b,
        unsigned short* __restrict__ yl, float* __restrict__ yr, int n) {
    constexpr int KSTEP = K / 32;
    constexpr int NT = PAD / 16;
    const int lane = threadIdx.x & 63;
    const int wid = (blockIdx.x * blockDim.x + threadIdx.x) >> 6;
    const int ntiles = (n + 15) >> 4;
    if (wid >= ntiles) return;
    const int nl = lane & 15, q = lane >> 4;

    // load B fragments + bias (once per wave)
    short8 Bl[NT][KSTEP], Br[NT][KSTEP];
    float biasv[NT];
#pragma unroll
    for (int t = 0; t < NT; ++t) {
        const int ncol = t * 16 + nl;
        biasv[t] = (ncol < F_OUT) ? b[ncol] : 0.f;
#pragma unroll
        for (int ks = 0; ks < KSTEP; ++ks) {
#pragma unroll
            for (int j = 0; j < 8; ++j) {
                const int k = ks * 32 + q * 8 + j;
                Bl[t][ks][j] = (ncol < F_OUT) ? (short)f2bf(Wl[k * F_OUT + ncol]) : (short)0;
                Br[t][ks][j] = (ncol < F_OUT) ? (short)f2bf(Wr[k * F_OUT + ncol]) : (short)0;
            }
        }
    }

    const int m0 = wid * 16;
    int m = m0 + nl; if (m >= n) m = n - 1;

    short8 a[KSTEP];
#pragma unroll
    for (int ks = 0; ks < KSTEP; ++ks) {
        if (AFP32) {
            const float* p = (const float*)Ain + (size_t)m * K + ks * 32 + q * 8;
#pragma unroll
            for (int j = 0; j < 8; ++j) a[ks][j] = (short)f2bf(p[j]);
        } else {
            union { uint4 u; short8 s; } cvt;
            cvt.u = *(const uint4*)((const unsigned short*)Ain + (size_t)m * K + ks * 32 + q * 8);
            a[ks] = cvt.s;
        }
    }

    floatx4 accl[NT], accr[NT];
#pragma unroll
    for (int t = 0; t < NT; ++t) { accl[t] = {0.f,0.f,0.f,0.f}; accr[t] = {0.f,0.f,0.f,0.f}; }
#pragma unroll
    for (int ks = 0; ks < KSTEP; ++ks) {
#pragma unroll
        for (int t = 0; t < NT; ++t) {
            accl[t] = __builtin_amdgcn_mfma_f32_16x16x32_bf16(a[ks], Bl[t][ks], accl[t], 0, 0, 0);
            accr[t] = __builtin_amdgcn_mfma_f32_16x16x32_bf16(a[ks], Br[t][ks], accr[t], 0, 0, 0);
        }
    }

#pragma unroll
    for (int t = 0; t < NT; ++t) {
        const int ncol = t * 16 + nl;
#pragma unroll
        for (int r = 0; r < 4; ++r) {
            const int node = m0 + q * 4 + r;
            if (node < n) {
                yl[(size_t)node * PAD + ncol] = f2bf(accl[t][r]);
                yr[(size_t)node * PAD + ncol] = accr[t][r] + biasv[t];
            }
        }
    }
}

// ---------------- aggregate: h = act(norm(mean_gather(yl) + yr)) ------------
// G = F/8 lanes per node (each lane owns 8 consecutive features in registers),
// 64/G nodes per wave. ACT: 1 = relu -> bf16 h ; 2 = log_softmax(10) -> fp32.
template <int F, int ACT>
__global__ __launch_bounds__(256) void agg_kernel(
        const unsigned short* __restrict__ yl, const float* __restrict__ yr,
        const int* __restrict__ rowptr, const int* __restrict__ degv,
        const int* __restrict__ col,
        unsigned short* __restrict__ hout, float* __restrict__ fout, int n) {
    constexpr int G = F / 8;
    constexpr int NPW = 64 / G;
    const int lane = threadIdx.x & 63;
    const int wid = (blockIdx.x * blockDim.x + threadIdx.x) >> 6;
    const int g = lane / G, c = lane % G;          // group lanes consecutive
    const int node = wid * NPW + g;
    if (node >= n) return;

    const int beg = rowptr[node];
    const int dg  = degv[node];
    const unsigned short* base = yl + c * 8;

    float a0=0.f,a1=0.f,a2=0.f,a3=0.f,a4=0.f,a5=0.f,a6=0.f,a7=0.f;
    int i = 0;
    for (; i + 2 <= dg; i += 2) {                   // 2 loads in flight
        const int n0 = col[beg + i], n1 = col[beg + i + 1];
        const uint4 t0 = *(const uint4*)(base + (size_t)n0 * F);
        const uint4 t1 = *(const uint4*)(base + (size_t)n1 * F);
        a0 += blo(t0.x) + blo(t1.x); a1 += bhi(t0.x) + bhi(t1.x);
        a2 += blo(t0.y) + blo(t1.y); a3 += bhi(t0.y) + bhi(t1.y);
        a4 += blo(t0.z) + blo(t1.z); a5 += bhi(t0.z) + bhi(t1.z);
        a6 += blo(t0.w) + blo(t1.w); a7 += bhi(t0.w) + bhi(t1.w);
    }
    if (i < dg) {
        const uint4 t0 = *(const uint4*)(base + (size_t)col[beg + i] * F);
        a0 += blo(t0.x); a1 += bhi(t0.x); a2 += blo(t0.y); a3 += bhi(t0.y);
        a4 += blo(t0.z); a5 += bhi(t0.z); a6 += blo(t0.w); a7 += bhi(t0.w);
    }
    const float inv = (dg > 0) ? 1.f / (float)dg : 0.f;

    const floatx4* yp = (const floatx4*)(yr + (size_t)node * F + c * 8);
    const floatx4 r0 = yp[0], r1 = yp[1];
    float o[8];
    o[0] = a0*inv + r0.x; o[1] = a1*inv + r0.y; o[2] = a2*inv + r0.z; o[3] = a3*inv + r0.w;
    o[4] = a4*inv + r1.x; o[5] = a5*inv + r1.y; o[6] = a6*inv + r1.z; o[7] = a7*inv + r1.w;

    float ss = 0.f;
#pragma unroll
    for (int j = 0; j < 8; ++j) ss += o[j] * o[j];
#pragma unroll
    for (int off = 1; off < G; off <<= 1) ss += __shfl_xor(ss, off);
    const float scale = 1.f / fmaxf(sqrtf(ss), 1e-12f);

    if (ACT == 1) {
        uint4 u;
        float h[8];
#pragma unroll
        for (int j = 0; j < 8; ++j) h[j] = fmaxf(o[j] * scale, 0.f);
        u.x = (unsigned)f2bf(h[0]) | ((unsigned)f2bf(h[1]) << 16);
        u.y = (unsigned)f2bf(h[2]) | ((unsigned)f2bf(h[3]) << 16);
        u.z = (unsigned)f2bf(h[4]) | ((unsigned)f2bf(h[5]) << 16);
        u.w = (unsigned)f2bf(h[6]) | ((unsigned)f2bf(h[7]) << 16);
        *(uint4*)(hout + (size_t)node * F + c * 8) = u;
    } else {
        // log_softmax over global cols 0..9 (F==16, G==2; pad cols are zero)
#pragma unroll
        for (int j = 0; j < 8; ++j) o[j] *= scale;
        const int cbase = c * 8;
        float m = -INFINITY;
#pragma unroll
        for (int j = 0; j < 8; ++j) if (cbase + j < 10) m = fmaxf(m, o[j]);
        m = fmaxf(m, __shfl_xor(m, 1));
        float s = 0.f;
#pragma unroll
        for (int j = 0; j < 8; ++j) if (cbase + j < 10) s += __expf(o[j] - m);
        s += __shfl_xor(s, 1);
        const float ls = logf(s);
#pragma unroll
        for (int j = 0; j < 8; ++j)
            if (cbase + j < 10) fout[(size_t)node * 10 + cbase + j] = o[j] - m - ls;
    }
}

extern "C" void kernel_launch(void* const* d_in, const int* in_sizes, int n_in,
                              void* d_out, int out_size, void* d_ws, size_t ws_size,
                              hipStream_t stream) {
    const float* x   = (const float*)d_in[0];
    const int*   ei  = (const int*)d_in[1];     // int64 in ref -> int32 on device
    const float* W1l = (const float*)d_in[2];
    const float* W1r = (const float*)d_in[3];
    const float* b1  = (const float*)d_in[4];
    const float* W2l = (const float*)d_in[5];
    const float* W2r = (const float*)d_in[6];
    const float* b2  = (const float*)d_in[7];
    const float* W3l = (const float*)d_in[8];
    const float* W3r = (const float*)d_in[9];
    const float* b3  = (const float*)d_in[10];
    float*       out = (float*)d_out;

    const int N = in_sizes[0] / 64;
    const int E = in_sizes[1] / 2;

    auto align16 = [](size_t v) { return (v + 15) & ~(size_t)15; };
    char* ws = (char*)d_ws;
    size_t off = 0;
    int* deg     = (int*)(ws + off); off = align16(off + (size_t)(N + 1) * 4);
    int* counter = deg + N;          // zeroed together with deg
    int* rowptr  = (int*)(ws + off); off = align16(off + (size_t)N * 4);
    int* cursor  = (int*)(ws + off); off = align16(off + (size_t)N * 4);
    int* colidx  = (int*)(ws + off); off = align16(off + (size_t)E * 4);
    unsigned short* y1l = (unsigned short*)(ws + off); off = align16(off + (size_t)N * 64 * 2);
    float*          y1r = (float*)(ws + off);          off = align16(off + (size_t)N * 64 * 4);
    unsigned short* h1  = (unsigned short*)(ws + off); off = align16(off + (size_t)N * 64 * 2);
    unsigned short* y2l = (unsigned short*)(ws + off); off = align16(off + (size_t)N * 32 * 2);
    float*          y2r = (float*)(ws + off);          off = align16(off + (size_t)N * 32 * 4);
    unsigned short* h2  = (unsigned short*)(ws + off); off = align16(off + (size_t)N * 32 * 2);
    unsigned short* y3l = (unsigned short*)(ws + off); off = align16(off + (size_t)N * 16 * 2);
    float*          y3r = (float*)(ws + off);          off = align16(off + (size_t)N * 16 * 4);
    (void)ws_size; (void)n_in; (void)out_size;

    // ---- CSR build
    hipMemsetAsync(deg, 0, (size_t)(N + 1) * 4, stream);
    degree_kernel<<<(E + 255) / 256, 256, 0, stream>>>(ei, deg, E);
    scan_block_kernel<<<(N + 1023) / 1024, 1024, 0, stream>>>(deg, rowptr, cursor, counter, N);
    build_csr_kernel<<<(E + 255) / 256, 256, 0, stream>>>(ei, cursor, colidx, E);

    const int ntiles = (N + 15) / 16;                  // MFMA node tiles
    const int tblocks = (ntiles * 64 + 255) / 256;     // 4 waves/block

    // layer 1
    transform_kernel<64, 64, 64, true><<<tblocks, 256, 0, stream>>>(x, W1l, W1r, b1, y1l, y1r, N);
    agg_kernel<64, 1><<<(N * 8 + 2047) / 2048 * 8, 256, 0, stream>>>(y1l, y1r, rowptr, deg, colidx, h1, nullptr, N);
    // layer 2
    transform_kernel<64, 32, 32, false><<<tblocks, 256, 0, stream>>>(h1, W2l, W2r, b2, y2l, y2r, N);
    agg_kernel<32, 1><<<(N + 63) / 64, 256, 0, stream>>>(y2l, y2r, rowptr, deg, colidx, h2, nullptr, N);
    // layer 3
    transform_kernel<32, 10, 16, false><<<tblocks, 256, 0, stream>>>(h2, W3l, W3r, b3, y3l, y3r, N);
    agg_kernel<16, 2><<<(N + 127) / 128, 256, 0, stream>>>(y3l, y3r, rowptr, deg, colidx, nullptr, out, N);
}

// Round 7
// 248.776 us; speedup vs baseline: 2.8520x; 1.4325x over previous
//
#include <hip/hip_runtime.h>
#include <math.h>

// ---------------------------------------------------------------------------
// GraphSAGE 3-layer forward.
//  - transforms: MFMA bf16 GEMM (16 nodes/wave), yl bf16 + yr fp32+bias
//  - aggregates: sub-wave-per-node register accumulation (R6)
//  - CSR build (R7): atomic-free 2-level bucket sort. R6 counters showed the
//    atomic scatter wrote 83MB for a 4.8MB array (random 4B stores -> full-line
//    writebacks across 8 non-coherent XCD L2s). Now every scatter is confined
//    to an LDS- or L2-resident window:
//      P1 hist: per-block LDS histogram over NBKT=ceil(N/512) dst-buckets
//      P2 bscan/bucketbase: exact disjoint (block,bucket) slices
//      P3 scatter: packed (dst&511)<<17|src via LDS cursors, short contiguous runs
//      P4 bucket_csr: per-bucket LDS hist+scan -> rowptr/deg; col scatter inside
//         the bucket's own ~24KB segment (lines fill fully before writeback)
//    Assumes N <= 2^17 (src packs in 17 bits) and NBKT <= 256.
// ---------------------------------------------------------------------------

typedef __attribute__((ext_vector_type(8))) short short8;
typedef __attribute__((ext_vector_type(4))) float floatx4;

__device__ __forceinline__ unsigned short f2bf(float f) {   // RNE
    unsigned u = __float_as_uint(f);
    u += 0x7fffu + ((u >> 16) & 1u);
    return (unsigned short)(u >> 16);
}
__device__ __forceinline__ float blo(unsigned u) { return __uint_as_float(u << 16); }
__device__ __forceinline__ float bhi(unsigned u) { return __uint_as_float(u & 0xffff0000u); }

// ---------------- CSR build (bucketed, atomic-free at global scope) ---------

// P1: per-block histogram of dst buckets. bh is bucket-major: bh[bucket*NB+blk].
__global__ __launch_bounds__(256) void hist_kernel(
        const int* __restrict__ ei, int* __restrict__ bh, int E, int NB, int NBKT) {
    __shared__ int lh[256];
    const int tid = threadIdx.x, blk = blockIdx.x;
    if (tid < NBKT) lh[tid] = 0;
    __syncthreads();
    const int base = blk << 12;
#pragma unroll
    for (int i = 0; i < 16; ++i) {
        const int e = base + (i << 8) + tid;
        if (e < E) atomicAdd(&lh[((unsigned)ei[E + e]) >> 9], 1);
    }
    __syncthreads();
    if (tid < NBKT) bh[tid * NB + blk] = lh[tid];
}

// P2a: per-bucket exclusive scan over blocks -> offs[bucket*NB+blk]; totals.
__global__ __launch_bounds__(256) void bscan_kernel(
        const int* __restrict__ bh, int* __restrict__ offs, int* __restrict__ btot,
        int NB, int NBKT) {
    const int lane = threadIdx.x & 63;
    const int w = blockIdx.x * 4 + (threadIdx.x >> 6);
    if (w >= NBKT) return;
    int running = 0;
    for (int base = 0; base < NB; base += 64) {
        const int j = base + lane;
        const int v = (j < NB) ? bh[w * NB + j] : 0;
        int incl = v;
#pragma unroll
        for (int off = 1; off < 64; off <<= 1) {
            const int t = __shfl_up(incl, off);
            if (lane >= off) incl += t;
        }
        if (j < NB) offs[w * NB + j] = running + incl - v;
        running += __shfl(incl, 63);
    }
    if (lane == 0) btot[w] = running;
}

// P2b: exclusive scan over bucket totals -> bucket_base[0..NBKT].
__global__ __launch_bounds__(64) void bucketbase_kernel(
        const int* __restrict__ btot, int* __restrict__ bucket_base, int NBKT) {
    const int lane = threadIdx.x;
    int running = 0;
    for (int base = 0; base < NBKT; base += 64) {
        const int j = base + lane;
        const int v = (j < NBKT) ? btot[j] : 0;
        int incl = v;
#pragma unroll
        for (int off = 1; off < 64; off <<= 1) {
            const int t = __shfl_up(incl, off);
            if (lane >= off) incl += t;
        }
        if (j < NBKT) bucket_base[j] = running + incl - v;
        running += __shfl(incl, 63);
    }
    if (lane == 0) bucket_base[NBKT] = running;
}

// P3: scatter packed edges into bucket-sorted order via LDS cursors.
__global__ __launch_bounds__(256) void scatter_kernel(
        const int* __restrict__ ei, const int* __restrict__ offs,
        const int* __restrict__ bucket_base, unsigned* __restrict__ ebuf,
        int E, int NB, int NBKT) {
    __shared__ int lcur[256];
    const int tid = threadIdx.x, blk = blockIdx.x;
    if (tid < NBKT) lcur[tid] = bucket_base[tid] + offs[tid * NB + blk];
    __syncthreads();
    const int base = blk << 12;
#pragma unroll
    for (int i = 0; i < 16; ++i) {
        const int e = base + (i << 8) + tid;
        if (e < E) {
            const int s = ei[e];
            const unsigned d = (unsigned)ei[E + e];
            const int p = atomicAdd(&lcur[d >> 9], 1);
            ebuf[p] = ((d & 511u) << 17) | (unsigned)s;
        }
    }
}

// P4: per-bucket CSR: LDS hist + scan over 512 local nodes -> rowptr/deg,
// then scatter col within the bucket's own segment.
__global__ __launch_bounds__(512) void bucket_csr_kernel(
        const unsigned* __restrict__ ebuf, const int* __restrict__ bucket_base,
        int* __restrict__ rowptr, int* __restrict__ deg, int* __restrict__ col,
        int N) {
    __shared__ int ldeg[512];
    __shared__ int buf[512];
    __shared__ int lcur[512];
    const int b = blockIdx.x, tid = threadIdx.x;
    const int segbase = bucket_base[b];
    const int L = bucket_base[b + 1] - segbase;
    ldeg[tid] = 0;
    __syncthreads();
    for (int i = tid; i < L; i += 512) atomicAdd(&ldeg[ebuf[segbase + i] >> 17], 1);
    __syncthreads();
    buf[tid] = ldeg[tid];
    __syncthreads();
    for (int off = 1; off < 512; off <<= 1) {
        const int t = (tid >= off) ? buf[tid - off] : 0;
        __syncthreads();
        buf[tid] += t;
        __syncthreads();
    }
    const int excl = buf[tid] - ldeg[tid];
    const int node = (b << 9) + tid;
    if (node < N) { rowptr[node] = segbase + excl; deg[node] = ldeg[tid]; }
    lcur[tid] = excl;
    __syncthreads();
    for (int i = tid; i < L; i += 512) {
        const unsigned p = ebuf[segbase + i];
        const int pos = atomicAdd(&lcur[p >> 17], 1);
        col[segbase + pos] = (int)(p & 0x1FFFFu);
    }
}

// ---------------- MFMA transform: y_l = A@Wl (bf16), y_r = A@Wr + b (fp32) ---
template <int K, int F_OUT, int PAD, bool AFP32>
__global__ __launch_bounds__(256) void transform_kernel(
        const void* __restrict__ Ain, const float* __restrict__ Wl,
        const float* __restrict__ Wr, const float* __restrict__ b,
        unsigned short* __restrict__ yl, float* __restrict__ yr, int n) {
    constexpr int KSTEP = K / 32;
    constexpr int NT = PAD / 16;
    const int lane = threadIdx.x & 63;
    const int wid = (blockIdx.x * blockDim.x + threadIdx.x) >> 6;
    const int ntiles = (n + 15) >> 4;
    if (wid >= ntiles) return;
    const int nl = lane & 15, q = lane >> 4;

    short8 Bl[NT][KSTEP], Br[NT][KSTEP];
    float biasv[NT];
#pragma unroll
    for (int t = 0; t < NT; ++t) {
        const int ncol = t * 16 + nl;
        biasv[t] = (ncol < F_OUT) ? b[ncol] : 0.f;
#pragma unroll
        for (int ks = 0; ks < KSTEP; ++ks) {
#pragma unroll
            for (int j = 0; j < 8; ++j) {
                const int k = ks * 32 + q * 8 + j;
                Bl[t][ks][j] = (ncol < F_OUT) ? (short)f2bf(Wl[k * F_OUT + ncol]) : (short)0;
                Br[t][ks][j] = (ncol < F_OUT) ? (short)f2bf(Wr[k * F_OUT + ncol]) : (short)0;
            }
        }
    }

    const int m0 = wid * 16;
    int m = m0 + nl; if (m >= n) m = n - 1;

    short8 a[KSTEP];
#pragma unroll
    for (int ks = 0; ks < KSTEP; ++ks) {
        if (AFP32) {
            const float* p = (const float*)Ain + (size_t)m * K + ks * 32 + q * 8;
#pragma unroll
            for (int j = 0; j < 8; ++j) a[ks][j] = (short)f2bf(p[j]);
        } else {
            union { uint4 u; short8 s; } cvt;
            cvt.u = *(const uint4*)((const unsigned short*)Ain + (size_t)m * K + ks * 32 + q * 8);
            a[ks] = cvt.s;
        }
    }

    floatx4 accl[NT], accr[NT];
#pragma unroll
    for (int t = 0; t < NT; ++t) { accl[t] = {0.f,0.f,0.f,0.f}; accr[t] = {0.f,0.f,0.f,0.f}; }
#pragma unroll
    for (int ks = 0; ks < KSTEP; ++ks) {
#pragma unroll
        for (int t = 0; t < NT; ++t) {
            accl[t] = __builtin_amdgcn_mfma_f32_16x16x32_bf16(a[ks], Bl[t][ks], accl[t], 0, 0, 0);
            accr[t] = __builtin_amdgcn_mfma_f32_16x16x32_bf16(a[ks], Br[t][ks], accr[t], 0, 0, 0);
        }
    }

#pragma unroll
    for (int t = 0; t < NT; ++t) {
        const int ncol = t * 16 + nl;
#pragma unroll
        for (int r = 0; r < 4; ++r) {
            const int node = m0 + q * 4 + r;
            if (node < n) {
                yl[(size_t)node * PAD + ncol] = f2bf(accl[t][r]);
                yr[(size_t)node * PAD + ncol] = accr[t][r] + biasv[t];
            }
        }
    }
}

// ---------------- aggregate: h = act(norm(mean_gather(yl) + yr)) ------------
template <int F, int ACT>
__global__ __launch_bounds__(256) void agg_kernel(
        const unsigned short* __restrict__ yl, const float* __restrict__ yr,
        const int* __restrict__ rowptr, const int* __restrict__ degv,
        const int* __restrict__ col,
        unsigned short* __restrict__ hout, float* __restrict__ fout, int n) {
    constexpr int G = F / 8;
    constexpr int NPW = 64 / G;
    const int lane = threadIdx.x & 63;
    const int wid = (blockIdx.x * blockDim.x + threadIdx.x) >> 6;
    const int g = lane / G, c = lane % G;
    const int node = wid * NPW + g;
    if (node >= n) return;

    const int beg = rowptr[node];
    const int dg  = degv[node];
    const unsigned short* base = yl + c * 8;

    float a0=0.f,a1=0.f,a2=0.f,a3=0.f,a4=0.f,a5=0.f,a6=0.f,a7=0.f;
    int i = 0;
    for (; i + 2 <= dg; i += 2) {
        const int n0 = col[beg + i], n1 = col[beg + i + 1];
        const uint4 t0 = *(const uint4*)(base + (size_t)n0 * F);
        const uint4 t1 = *(const uint4*)(base + (size_t)n1 * F);
        a0 += blo(t0.x) + blo(t1.x); a1 += bhi(t0.x) + bhi(t1.x);
        a2 += blo(t0.y) + blo(t1.y); a3 += bhi(t0.y) + bhi(t1.y);
        a4 += blo(t0.z) + blo(t1.z); a5 += bhi(t0.z) + bhi(t1.z);
        a6 += blo(t0.w) + blo(t1.w); a7 += bhi(t0.w) + bhi(t1.w);
    }
    if (i < dg) {
        const uint4 t0 = *(const uint4*)(base + (size_t)col[beg + i] * F);
        a0 += blo(t0.x); a1 += bhi(t0.x); a2 += blo(t0.y); a3 += bhi(t0.y);
        a4 += blo(t0.z); a5 += bhi(t0.z); a6 += blo(t0.w); a7 += bhi(t0.w);
    }
    const float inv = (dg > 0) ? 1.f / (float)dg : 0.f;

    const floatx4* yp = (const floatx4*)(yr + (size_t)node * F + c * 8);
    const floatx4 r0 = yp[0], r1 = yp[1];
    float o[8];
    o[0] = a0*inv + r0.x; o[1] = a1*inv + r0.y; o[2] = a2*inv + r0.z; o[3] = a3*inv + r0.w;
    o[4] = a4*inv + r1.x; o[5] = a5*inv + r1.y; o[6] = a6*inv + r1.z; o[7] = a7*inv + r1.w;

    float ss = 0.f;
#pragma unroll
    for (int j = 0; j < 8; ++j) ss += o[j] * o[j];
#pragma unroll
    for (int off = 1; off < G; off <<= 1) ss += __shfl_xor(ss, off);
    const float scale = 1.f / fmaxf(sqrtf(ss), 1e-12f);

    if (ACT == 1) {
        uint4 u;
        float h[8];
#pragma unroll
        for (int j = 0; j < 8; ++j) h[j] = fmaxf(o[j] * scale, 0.f);
        u.x = (unsigned)f2bf(h[0]) | ((unsigned)f2bf(h[1]) << 16);
        u.y = (unsigned)f2bf(h[2]) | ((unsigned)f2bf(h[3]) << 16);
        u.z = (unsigned)f2bf(h[4]) | ((unsigned)f2bf(h[5]) << 16);
        u.w = (unsigned)f2bf(h[6]) | ((unsigned)f2bf(h[7]) << 16);
        *(uint4*)(hout + (size_t)node * F + c * 8) = u;
    } else {
#pragma unroll
        for (int j = 0; j < 8; ++j) o[j] *= scale;
        const int cbase = c * 8;
        float m = -INFINITY;
#pragma unroll
        for (int j = 0; j < 8; ++j) if (cbase + j < 10) m = fmaxf(m, o[j]);
        m = fmaxf(m, __shfl_xor(m, 1));
        float s = 0.f;
#pragma unroll
        for (int j = 0; j < 8; ++j) if (cbase + j < 10) s += __expf(o[j] - m);
        s += __shfl_xor(s, 1);
        const float ls = logf(s);
#pragma unroll
        for (int j = 0; j < 8; ++j)
            if (cbase + j < 10) fout[(size_t)node * 10 + cbase + j] = o[j] - m - ls;
    }
}

extern "C" void kernel_launch(void* const* d_in, const int* in_sizes, int n_in,
                              void* d_out, int out_size, void* d_ws, size_t ws_size,
                              hipStream_t stream) {
    const float* x   = (const float*)d_in[0];
    const int*   ei  = (const int*)d_in[1];     // int64 in ref -> int32 on device
    const float* W1l = (const float*)d_in[2];
    const float* W1r = (const float*)d_in[3];
    const float* b1  = (const float*)d_in[4];
    const float* W2l = (const float*)d_in[5];
    const float* W2r = (const float*)d_in[6];
    const float* b2  = (const float*)d_in[7];
    const float* W3l = (const float*)d_in[8];
    const float* W3r = (const float*)d_in[9];
    const float* b3  = (const float*)d_in[10];
    float*       out = (float*)d_out;

    const int N = in_sizes[0] / 64;
    const int E = in_sizes[1] / 2;
    const int NBKT = (N + 511) >> 9;     // dst buckets of 512 nodes (<=256)
    const int NB   = (E + 4095) >> 12;   // 4096 edges per hist/scatter block

    auto align16 = [](size_t v) { return (v + 15) & ~(size_t)15; };
    char* ws = (char*)d_ws;
    size_t off = 0;
    int* rowptr  = (int*)(ws + off); off = align16(off + (size_t)N * 4);
    int* deg     = (int*)(ws + off); off = align16(off + (size_t)N * 4);
    int* colidx  = (int*)(ws + off); off = align16(off + (size_t)E * 4);
    unsigned* ebuf = (unsigned*)(ws + off); off = align16(off + (size_t)E * 4);
    int* bh      = (int*)(ws + off); off = align16(off + (size_t)NBKT * NB * 4);
    int* offsb   = (int*)(ws + off); off = align16(off + (size_t)NBKT * NB * 4);
    int* btot    = (int*)(ws + off); off = align16(off + (size_t)NBKT * 4);
    int* bbase   = (int*)(ws + off); off = align16(off + (size_t)(NBKT + 1) * 4);
    unsigned short* y1l = (unsigned short*)(ws + off); off = align16(off + (size_t)N * 64 * 2);
    float*          y1r = (float*)(ws + off);          off = align16(off + (size_t)N * 64 * 4);
    unsigned short* h1  = (unsigned short*)(ws + off); off = align16(off + (size_t)N * 64 * 2);
    unsigned short* y2l = (unsigned short*)(ws + off); off = align16(off + (size_t)N * 32 * 2);
    float*          y2r = (float*)(ws + off);          off = align16(off + (size_t)N * 32 * 4);
    unsigned short* h2  = (unsigned short*)(ws + off); off = align16(off + (size_t)N * 32 * 2);
    unsigned short* y3l = (unsigned short*)(ws + off); off = align16(off + (size_t)N * 16 * 2);
    float*          y3r = (float*)(ws + off);          off = align16(off + (size_t)N * 16 * 4);
    (void)ws_size; (void)n_in; (void)out_size;

    // ---- CSR build (atomic-free bucket sort; no memsets needed)
    hist_kernel<<<NB, 256, 0, stream>>>(ei, bh, E, NB, NBKT);
    bscan_kernel<<<(NBKT + 3) / 4, 256, 0, stream>>>(bh, offsb, btot, NB, NBKT);
    bucketbase_kernel<<<1, 64, 0, stream>>>(btot, bbase, NBKT);
    scatter_kernel<<<NB, 256, 0, stream>>>(ei, offsb, bbase, ebuf, E, NB, NBKT);
    bucket_csr_kernel<<<NBKT, 512, 0, stream>>>(ebuf, bbase, rowptr, deg, colidx, N);

    const int ntiles = (N + 15) / 16;                  // MFMA node tiles
    const int tblocks = (ntiles * 64 + 255) / 256;     // 4 waves/block

    // layer 1
    transform_kernel<64, 64, 64, true><<<tblocks, 256, 0, stream>>>(x, W1l, W1r, b1, y1l, y1r, N);
    agg_kernel<64, 1><<<(N + 31) / 32, 256, 0, stream>>>(y1l, y1r, rowptr, deg, colidx, h1, nullptr, N);
    // layer 2
    transform_kernel<64, 32, 32, false><<<tblocks, 256, 0, stream>>>(h1, W2l, W2r, b2, y2l, y2r, N);
    agg_kernel<32, 1><<<(N + 63) / 64, 256, 0, stream>>>(y2l, y2r, rowptr, deg, colidx, h2, nullptr, N);
    // layer 3
    transform_kernel<32, 10, 16, false><<<tblocks, 256, 0, stream>>>(h2, W3l, W3r, b3, y3l, y3r, N);
    agg_kernel<16, 2><<<(N + 127) / 128, 256, 0, stream>>>(y3l, y3r, rowptr, deg, colidx, nullptr, out, N);
}